// Round 1
// baseline (137.818 us; speedup 1.0000x reference)
//
#include <hip/hip_runtime.h>
#include <math.h>

// Problem constants (from setup_inputs): bs=64, n=16384, dx=128, dy=256
#define BS     64
#define NN     16384
#define DX     128
#define DY     256
#define ZDIM   (4 * DX)          // 512
#define NCHUNK 32
#define ROWS_PER_CHUNK (NN / NCHUNK)   // 512

// ---------------------------------------------------------------------------
// Kernel 1: per-(batch, chunk) partial stats.
// Grid: (BS, NCHUNK), block: 256 threads.
// Thread t handles column quad q = t&31 (cols 4q..4q+3), row-group rg = t>>5
// (rows rg, rg+8, rg+16, ... within the chunk). float4 loads are fully
// coalesced: 32 consecutive lanes cover one contiguous 128-col row (512 B).
// Partials written to ws as ws[b][c][comp][d], comp: 0=sum 1=sumsq 2=min 3=max
// ---------------------------------------------------------------------------
__global__ __launch_bounds__(256) void stats_partial(
    const float* __restrict__ X, float* __restrict__ ws) {
    const int b = blockIdx.x;
    const int c = blockIdx.y;
    const int t = threadIdx.x;
    const int q = t & 31;    // column quad
    const int rg = t >> 5;   // row group 0..7

    const float4* __restrict__ Xb = (const float4*)(
        X + (size_t)b * NN * DX + (size_t)c * ROWS_PER_CHUNK * DX);

    float s0 = 0.f, s1 = 0.f, s2 = 0.f, s3 = 0.f;       // sum
    float p0 = 0.f, p1 = 0.f, p2 = 0.f, p3 = 0.f;       // sum of squares
    float mn0 = INFINITY, mn1 = INFINITY, mn2 = INFINITY, mn3 = INFINITY;
    float mx0 = -INFINITY, mx1 = -INFINITY, mx2 = -INFINITY, mx3 = -INFINITY;

    #pragma unroll 4
    for (int i = rg; i < ROWS_PER_CHUNK; i += 8) {
        float4 v = Xb[i * 32 + q];
        s0 += v.x; p0 += v.x * v.x; mn0 = fminf(mn0, v.x); mx0 = fmaxf(mx0, v.x);
        s1 += v.y; p1 += v.y * v.y; mn1 = fminf(mn1, v.y); mx1 = fmaxf(mx1, v.y);
        s2 += v.z; p2 += v.z * v.z; mn2 = fminf(mn2, v.z); mx2 = fmaxf(mx2, v.z);
        s3 += v.w; p3 += v.w * v.w; mn3 = fminf(mn3, v.w); mx3 = fmaxf(mx3, v.w);
    }

    // LDS: [row-group][quad][16 values: sum0..3, sumsq0..3, min0..3, max0..3]
    __shared__ float lds[8][32][16];
    float* L = lds[rg][q];
    L[0] = s0;  L[1] = s1;  L[2] = s2;  L[3] = s3;
    L[4] = p0;  L[5] = p1;  L[6] = p2;  L[7] = p3;
    L[8] = mn0; L[9] = mn1; L[10] = mn2; L[11] = mn3;
    L[12] = mx0; L[13] = mx1; L[14] = mx2; L[15] = mx3;
    __syncthreads();

    // Reduce across the 8 row-groups. 512 (comp,d) outputs, 2 per thread.
    for (int v = t; v < 512; v += 256) {
        const int comp = v >> 7;       // 0..3
        const int d = v & 127;
        const int qq = d >> 2;
        const int idx = comp * 4 + (d & 3);
        float r = lds[0][qq][idx];
        #pragma unroll
        for (int k = 1; k < 8; ++k) {
            const float x = lds[k][qq][idx];
            if (comp < 2)       r += x;
            else if (comp == 2) r = fminf(r, x);
            else                r = fmaxf(r, x);
        }
        ws[(((size_t)b * NCHUNK + c) * 4 + comp) * DX + d] = r;
    }
}

// ---------------------------------------------------------------------------
// Kernel 2: reduce chunk partials -> z[512] in LDS -> out = z @ W^T + bias.
// Grid: BS blocks, 256 threads each. W rows are L2/L3-resident (512 KB).
// ---------------------------------------------------------------------------
__global__ __launch_bounds__(256) void finalize(
    const float* __restrict__ ws, const float* __restrict__ W,
    const float* __restrict__ bias, float* __restrict__ out) {
    const int b = blockIdx.x;
    const int t = threadIdx.x;

    __shared__ float red[512];  // [sum(128), sumsq(128), min(128), max(128)]
    __shared__ float z[512];    // [mean, min, max, std]

    for (int v = t; v < 512; v += 256) {
        const int comp = v >> 7;
        const int d = v & 127;
        const float* p = ws + (((size_t)b * NCHUNK) * 4 + comp) * DX + d;
        float r = p[0];
        #pragma unroll 4
        for (int c = 1; c < NCHUNK; ++c) {
            const float x = p[(size_t)c * 512];
            if (comp < 2)       r += x;
            else if (comp == 2) r = fminf(r, x);
            else                r = fmaxf(r, x);
        }
        red[v] = r;
    }
    __syncthreads();

    if (t < DX) {
        const float s  = red[t];
        const float ss = red[DX + t];
        const float mean = s / (float)NN;
        const float var  = (ss - s * s / (float)NN) / (float)(NN - 1);
        z[t]            = mean;              // mean
        z[DX + t]       = red[2 * DX + t];   // min
        z[2 * DX + t]   = red[3 * DX + t];   // max
        z[3 * DX + t]   = sqrtf(fmaxf(var, 0.f));  // std (ddof=1)
    }
    __syncthreads();

    // out[b][o] = bias[o] + dot(z, W[o][:])
    const int o = t;  // 256 outputs, 256 threads
    const float4* __restrict__ Wr = (const float4*)(W + (size_t)o * ZDIM);
    const float4* __restrict__ zz = (const float4*)z;
    float acc = bias[o];
    #pragma unroll 8
    for (int k = 0; k < ZDIM / 4; ++k) {
        const float4 w4 = Wr[k];
        const float4 zv = zz[k];
        acc += w4.x * zv.x + w4.y * zv.y + w4.z * zv.z + w4.w * zv.w;
    }
    out[(size_t)b * DY + o] = acc;
}

extern "C" void kernel_launch(void* const* d_in, const int* in_sizes, int n_in,
                              void* d_out, int out_size, void* d_ws, size_t ws_size,
                              hipStream_t stream) {
    const float* X    = (const float*)d_in[0];   // [64, 16384, 128] fp32
    const float* W    = (const float*)d_in[1];   // [256, 512] fp32
    const float* bias = (const float*)d_in[2];   // [256] fp32
    float* out        = (float*)d_out;           // [64, 256] fp32
    float* ws         = (float*)d_ws;            // needs 64*32*4*128*4 B = 4 MiB

    dim3 grid1(BS, NCHUNK);
    stats_partial<<<grid1, 256, 0, stream>>>(X, ws);
    finalize<<<BS, 256, 0, stream>>>(ws, W, bias, out);
}

// Round 3
// 110.971 us; speedup vs baseline: 1.2419x; 1.2419x over previous
//
#include <hip/hip_runtime.h>
#include <math.h>

// Problem constants: bs=64, n=16384, dx=128, dy=256
#define BS     64
#define NN     16384
#define DX     128
#define DY     256
#define ZDIM   (4 * DX)          // 512
#define NCHUNK 32
#define ROWS_PER_CHUNK (NN / NCHUNK)   // 512

typedef float floatx4 __attribute__((ext_vector_type(4)));

// ---------------------------------------------------------------------------
// Kernel 1: per-(batch, chunk) partial stats. Grid (BS, NCHUNK) = 2048 blocks
// = 8 blocks/CU. Thread t: column quad q=t&31, row-group rg=t>>5 owns a
// CONTIGUOUS span of 64 rows so each thread streams at 512B stride inside one
// DRAM page; a wave reads 1KB contiguous per step. Nontemporal loads keep the
// one-pass stream from polluting L2.
// ws[b][c][comp][d], comp: 0=sum 1=sumsq 2=min 3=max
// ---------------------------------------------------------------------------
__global__ __launch_bounds__(256) void stats_partial(
    const float* __restrict__ X, float* __restrict__ ws) {
    const int b = blockIdx.x;
    const int c = blockIdx.y;
    const int t = threadIdx.x;
    const int q = t & 31;    // column quad
    const int rg = t >> 5;   // row group 0..7 -> rows [rg*64, rg*64+64)

    const floatx4* __restrict__ Xt = (const floatx4*)(
        X + (size_t)b * NN * DX + (size_t)c * ROWS_PER_CHUNK * DX) +
        (size_t)rg * 64 * 32 + q;

    float s0 = 0.f, s1 = 0.f, s2 = 0.f, s3 = 0.f;       // sum
    float p0 = 0.f, p1 = 0.f, p2 = 0.f, p3 = 0.f;       // sum of squares
    float mn0 = INFINITY, mn1 = INFINITY, mn2 = INFINITY, mn3 = INFINITY;
    float mx0 = -INFINITY, mx1 = -INFINITY, mx2 = -INFINITY, mx3 = -INFINITY;

    #pragma unroll 8
    for (int s = 0; s < 64; ++s) {
        floatx4 v = __builtin_nontemporal_load(Xt + (size_t)s * 32);
        s0 += v.x; p0 += v.x * v.x; mn0 = fminf(mn0, v.x); mx0 = fmaxf(mx0, v.x);
        s1 += v.y; p1 += v.y * v.y; mn1 = fminf(mn1, v.y); mx1 = fmaxf(mx1, v.y);
        s2 += v.z; p2 += v.z * v.z; mn2 = fminf(mn2, v.z); mx2 = fmaxf(mx2, v.z);
        s3 += v.w; p3 += v.w * v.w; mn3 = fminf(mn3, v.w); mx3 = fmaxf(mx3, v.w);
    }

    // LDS: [row-group][quad][16: sum0..3, sumsq0..3, min0..3, max0..3]
    __shared__ float lds[8][32][16];
    float* L = lds[rg][q];
    L[0] = s0;  L[1] = s1;  L[2] = s2;  L[3] = s3;
    L[4] = p0;  L[5] = p1;  L[6] = p2;  L[7] = p3;
    L[8] = mn0; L[9] = mn1; L[10] = mn2; L[11] = mn3;
    L[12] = mx0; L[13] = mx1; L[14] = mx2; L[15] = mx3;
    __syncthreads();

    // Reduce across the 8 row-groups. 512 (comp,d) outputs, 2 per thread.
    for (int v = t; v < 512; v += 256) {
        const int comp = v >> 7;       // 0..3
        const int d = v & 127;
        const int qq = d >> 2;
        const int idx = comp * 4 + (d & 3);
        float r = lds[0][qq][idx];
        #pragma unroll
        for (int k = 1; k < 8; ++k) {
            const float x = lds[k][qq][idx];
            if (comp < 2)       r += x;
            else if (comp == 2) r = fminf(r, x);
            else                r = fmaxf(r, x);
        }
        ws[(((size_t)b * NCHUNK + c) * 4 + comp) * DX + d] = r;
    }
}

// ---------------------------------------------------------------------------
// Kernel 2: reduce 32 chunk partials per (batch, comp). Grid (BS, 4) = 256
// blocks, 128 threads (t = d, coalesced 512B per step).
// Writes ws2[b][comp][d] at byte offset 4MiB into d_ws.
// ---------------------------------------------------------------------------
__global__ __launch_bounds__(128) void reduce_chunks(
    const float* __restrict__ ws, float* __restrict__ ws2) {
    const int b = blockIdx.x;
    const int comp = blockIdx.y;
    const int d = threadIdx.x;   // 0..127

    const float* __restrict__ p =
        ws + (((size_t)b * NCHUNK) * 4 + comp) * DX + d;
    float r = p[0];
    #pragma unroll 8
    for (int c = 1; c < NCHUNK; ++c) {
        const float x = p[(size_t)c * 512];
        if (comp < 2)       r += x;
        else if (comp == 2) r = fminf(r, x);
        else                r = fmaxf(r, x);
    }
    ws2[((size_t)b * 4 + comp) * DX + d] = r;
}

// ---------------------------------------------------------------------------
// Kernel 3: build z[512] and out = z @ W^T + bias. Grid BS, 256 threads.
// W (512KB) is L2/L3-resident across the 64 blocks.
// ---------------------------------------------------------------------------
__global__ __launch_bounds__(256) void gemm_finalize(
    const float* __restrict__ ws2, const float* __restrict__ W,
    const float* __restrict__ bias, float* __restrict__ out) {
    const int b = blockIdx.x;
    const int t = threadIdx.x;

    __shared__ float z[512];    // [mean, min, max, std]

    // ws2[b][comp][d], comp 0=sum 1=sumsq 2=min 3=max
    for (int v = t; v < 512; v += 256) {
        const int comp = v >> 7;
        const int d = v & 127;
        const float x = ws2[((size_t)b * 4 + comp) * DX + d];
        if (comp == 0) {
            const float s  = x;
            const float ss = ws2[((size_t)b * 4 + 1) * DX + d];
            const float mean = s / (float)NN;
            const float var  = (ss - s * s / (float)NN) / (float)(NN - 1);
            z[d]          = mean;
            z[3 * DX + d] = sqrtf(fmaxf(var, 0.f));
        } else if (comp == 2) {
            z[DX + d] = x;          // min
        } else if (comp == 3) {
            z[2 * DX + d] = x;      // max
        }
        // comp==1 folded into comp==0's thread
    }
    __syncthreads();

    // out[b][o] = bias[o] + dot(z, W[o][:])
    const int o = t;  // 256 outputs, 256 threads
    const float4* __restrict__ Wr = (const float4*)(W + (size_t)o * ZDIM);
    const float4* __restrict__ zz = (const float4*)z;
    float acc = bias[o];
    #pragma unroll 8
    for (int k = 0; k < ZDIM / 4; ++k) {
        const float4 w4 = Wr[k];
        const float4 zv = zz[k];
        acc += w4.x * zv.x + w4.y * zv.y + w4.z * zv.z + w4.w * zv.w;
    }
    out[(size_t)b * DY + o] = acc;
}

extern "C" void kernel_launch(void* const* d_in, const int* in_sizes, int n_in,
                              void* d_out, int out_size, void* d_ws, size_t ws_size,
                              hipStream_t stream) {
    const float* X    = (const float*)d_in[0];   // [64, 16384, 128] fp32
    const float* W    = (const float*)d_in[1];   // [256, 512] fp32
    const float* bias = (const float*)d_in[2];   // [256] fp32
    float* out        = (float*)d_out;           // [64, 256] fp32
    float* ws         = (float*)d_ws;            // partials: 4 MiB
    float* ws2        = (float*)((char*)d_ws + (4u << 20));  // reduced: 128 KB

    dim3 grid1(BS, NCHUNK);
    stats_partial<<<grid1, 256, 0, stream>>>(X, ws);
    dim3 grid2(BS, 4);
    reduce_chunks<<<grid2, 128, 0, stream>>>(ws, ws2);
    gemm_finalize<<<BS, 256, 0, stream>>>(ws2, W, bias, out);
}